// Round 18
// baseline (1844.287 us; speedup 1.0000x reference)
//
#include <hip/hip_runtime.h>
#include <hip/hip_bf16.h>
#include <stdint.h>

#define T_TOK 8192
#define HID   2048
#define FFN   1024
#define NEXP  64
#define ETOT  72
#define NPAD  80
#define TOPK  8
#define NASSIGN (T_TOK*TOPK)

typedef unsigned short u16;
typedef __bf16 bf16;
typedef bf16 bf16x8 __attribute__((ext_vector_type(8)));
typedef float f32x4 __attribute__((ext_vector_type(4)));

typedef const __attribute__((address_space(1))) void* gp_t;
typedef __attribute__((address_space(3))) void* lp_t;

__device__ __forceinline__ void gload16(const void* g, void* lds) {
  __builtin_amdgcn_global_load_lds((gp_t)g, (lp_t)lds, 16, 0, 0);
}
__device__ __forceinline__ f32x4 mfma16(bf16x8 a, bf16x8 b, f32x4 c) {
  return __builtin_amdgcn_mfma_f32_16x16x32_bf16(a, b, c, 0, 0, 0);
}

union U8 { bf16 h[8]; uint4 u; };
union U2 { bf16 h[2]; unsigned int u; };

// ---------------- K0: fp32 -> bf16 hi/lo split of x ----------------
__global__ void k_prep_x(const float* __restrict__ x, u16* __restrict__ xh,
                         u16* __restrict__ xl, int n8) {
  int i = blockIdx.x * blockDim.x + threadIdx.x;
  int stride = gridDim.x * blockDim.x;
  for (; i < n8; i += stride) {
    const float4* p = (const float4*)(x + (size_t)i * 8);
    float4 a = p[0], b = p[1];
    float f[8] = {a.x,a.y,a.z,a.w,b.x,b.y,b.z,b.w};
    U8 hh, ll;
#pragma unroll
    for (int j = 0; j < 8; j++) {
      bf16 h = (bf16)f[j];
      hh.h[j] = h;
      ll.h[j] = (bf16)(f[j] - (float)h);
    }
    ((uint4*)xh)[i] = hh.u;
    ((uint4*)xl)[i] = ll.u;
  }
}

// ---------------- K0b: gate_w -> bf16 hi/lo, padded to 80 rows ----------------
__global__ void k_prep_gate(const float* __restrict__ gw, u16* __restrict__ gh,
                            u16* __restrict__ gl) {
  int e = blockIdx.x;
  for (int k8 = threadIdx.x; k8 < HID/8; k8 += blockDim.x) {
    U8 hh, ll;
    if (e < ETOT) {
      const float4* p = (const float4*)(gw + (size_t)e*HID + k8*8);
      float4 a = p[0], b = p[1];
      float f[8] = {a.x,a.y,a.z,a.w,b.x,b.y,b.z,b.w};
#pragma unroll
      for (int j = 0; j < 8; j++) {
        bf16 h = (bf16)f[j]; hh.h[j] = h; ll.h[j] = (bf16)(f[j]-(float)h);
      }
    } else {
      hh.u = make_uint4(0,0,0,0); ll.u = make_uint4(0,0,0,0);
    }
    ((uint4*)gh)[(size_t)e*(HID/8) + k8] = hh.u;
    ((uint4*)gl)[(size_t)e*(HID/8) + k8] = ll.u;
  }
}

// ---------------- K0c: fp32 [R][C] -> bf16 [C][R] transpose-convert ----------
__global__ void k_convT(const float* __restrict__ src, u16* __restrict__ dst,
                        int R, int C) {
  int e = blockIdx.z;
  src += (size_t)e * R * C;
  dst += (size_t)e * R * C;
  int c0 = blockIdx.x * 64, r0 = blockIdx.y * 128;
  __shared__ u16 t[64 * 134];
  int tid = threadIdx.x;
  int rr = tid >> 4, cc = (tid & 15) * 4;
#pragma unroll
  for (int it = 0; it < 8; it++) {
    int r = it * 16 + rr;
    float4 v = *(const float4*)(src + (size_t)(r0 + r) * C + c0 + cc);
    const float* f = &v.x;
#pragma unroll
    for (int i = 0; i < 4; i++) {
      U2 u; u.h[0] = (bf16)f[i]; u.h[1] = (bf16)0.f;
      t[(cc + i) * 134 + r] = (u16)(u.u & 0xffffu);
    }
  }
  __syncthreads();
  int n = tid >> 2, kb = (tid & 3) * 32;
  u16* drow = dst + (size_t)(c0 + n) * R + r0 + kb;
  const u16* srow = &t[n * 134 + kb];
#pragma unroll
  for (int j = 0; j < 2; j++) {
    uint2 a = *(const uint2*)&srow[j*16 + 0];
    uint2 b = *(const uint2*)&srow[j*16 + 4];
    uint2 c = *(const uint2*)&srow[j*16 + 8];
    uint2 d = *(const uint2*)&srow[j*16 + 12];
    *(uint4*)&drow[j*16]     = make_uint4(a.x, a.y, b.x, b.y);
    *(uint4*)&drow[j*16 + 8] = make_uint4(c.x, c.y, d.x, d.y);
  }
}

// ---------------- K1: router ----------------
__global__ void k_router(const u16* __restrict__ xh, const u16* __restrict__ xl,
                         const u16* __restrict__ gh, const u16* __restrict__ gl,
                         float* __restrict__ logits_out, int* __restrict__ tk_idx,
                         float* __restrict__ tk_w, int* __restrict__ counts) {
  __shared__ u16 la_h[64*32], la_l[64*32], lb_h[NPAD*32], lb_l[NPAD*32];
  __shared__ float llog[64*NPAD];
  int tid = threadIdx.x, lane = tid & 63, wid = tid >> 6;
  int t0 = blockIdx.x * 64;
  int rsub = lane >> 2, csub = lane & 3;
  f32x4 acc[5] = {};
#pragma unroll 1
  for (int k0 = 0; k0 < HID; k0 += 32) {
    int arow = wid*16 + rsub;
    gload16(xh + (size_t)(t0+arow)*HID + k0 + csub*8, &la_h[wid*512]);
    gload16(xl + (size_t)(t0+arow)*HID + k0 + csub*8, &la_l[wid*512]);
    int brow = wid*16 + rsub;
    gload16(gh + (size_t)brow*HID + k0 + csub*8, &lb_h[wid*512]);
    gload16(gl + (size_t)brow*HID + k0 + csub*8, &lb_l[wid*512]);
    if (wid == 0) gload16(gh + (size_t)(64+rsub)*HID + k0 + csub*8, &lb_h[4*512]);
    if (wid == 1) gload16(gl + (size_t)(64+rsub)*HID + k0 + csub*8, &lb_l[4*512]);
    __syncthreads();
    int ar = wid*16 + (lane & 15);
    int ks = lane >> 4;
    bf16x8 ah = *(const bf16x8*)&la_h[ar*32 + ks*8];
    bf16x8 al = *(const bf16x8*)&la_l[ar*32 + ks*8];
#pragma unroll
    for (int nf = 0; nf < 5; nf++) {
      int br = nf*16 + (lane & 15);
      bf16x8 bh = *(const bf16x8*)&lb_h[br*32 + ks*8];
      bf16x8 bl = *(const bf16x8*)&lb_l[br*32 + ks*8];
      acc[nf] = mfma16(ah, bh, acc[nf]);
      acc[nf] = mfma16(ah, bl, acc[nf]);
      acc[nf] = mfma16(al, bh, acc[nf]);
    }
    __syncthreads();
  }
  {
    int q = lane >> 4, c = lane & 15;
#pragma unroll
    for (int nf = 0; nf < 5; nf++)
#pragma unroll
      for (int r = 0; r < 4; r++)
        llog[(wid*16 + q*4 + r)*NPAD + nf*16 + c] = acc[nf][r];
  }
  __syncthreads();
  if (tid < 64) {
    int t = t0 + tid;
    float* lg = &llog[tid*NPAD];
    float m = -1e30f;
    for (int e = 0; e < ETOT; e++) {
      float v = lg[e];
      logits_out[(size_t)t*ETOT + e] = v;
      m = fmaxf(m, v);
    }
    float s = 0.f;
    for (int e = 0; e < ETOT; e++) s += __expf(lg[e] - m);
    uint64_t m0 = 0; unsigned int m1 = 0;
    for (int k = 0; k < TOPK; k++) {
      float best = -1e30f; int bi = 0;
      for (int e = 0; e < ETOT; e++) {
        bool used = (e < 64) ? ((m0 >> e) & 1) : ((m1 >> (e-64)) & 1);
        float v = lg[e];
        if (!used && v > best) { best = v; bi = e; }
      }
      if (bi < 64) m0 |= (1ull << bi); else m1 |= (1u << (bi-64));
      tk_idx[t*TOPK + k] = bi;
      tk_w[t*TOPK + k] = __expf(best - m) / s;
      if (bi < NEXP) atomicAdd(&counts[bi], 1);
    }
  }
}

// ---------------- K2: scan ----------------
__global__ void k_scan(const int* __restrict__ counts, int* __restrict__ offsets,
                       int* __restrict__ cursors) {
  if (threadIdx.x == 0) {
    int s = 0;
    for (int e = 0; e < NEXP; e++) { offsets[e] = s; cursors[e] = s; s += counts[e]; }
  }
}

// ---------------- K3: build grouped lists (+ per-token slot map) ----------------
__global__ void k_build(const int* __restrict__ tk_idx, const float* __restrict__ tk_w,
                        int* __restrict__ cursors, int* __restrict__ rows,
                        float* __restrict__ rwgt, int* __restrict__ slots) {
  int t = blockIdx.x * blockDim.x + threadIdx.x;
  if (t >= T_TOK) return;
#pragma unroll
  for (int k = 0; k < TOPK; k++) {
    int e = tk_idx[t*TOPK + k];
    if (e < NEXP) {
      int p = atomicAdd(&cursors[e], 1);
      rows[p] = t;
      rwgt[p] = tk_w[t*TOPK + k];
      slots[t*TOPK + k] = p;
    } else {
      slots[t*TOPK + k] = -1;
    }
  }
}

// Shared fragment-compute body (r10/r12-verified math).
#define FRAG_COMPUTE(LAP, LBP) do { \
    bf16x8 afr[4], bfr[4]; \
    _Pragma("unroll") \
    for (int i = 0; i < 4; i++) { \
      int row = wm + i*16 + (lane & 15); \
      int ch = (lane >> 4) ^ ((row >> 1) & 3); \
      afr[i] = *(const bf16x8*)&(LAP)[row*32 + ch*8]; \
      int n = wn + i*16 + (lane & 15); \
      int chb = (lane >> 4) ^ ((n >> 1) & 3); \
      bfr[i] = *(const bf16x8*)&(LBP)[n*32 + chb*8]; \
    } \
    _Pragma("unroll") \
    for (int nf = 0; nf < 4; nf++) \
      _Pragma("unroll") \
      for (int mf = 0; mf < 4; mf++) \
        acc[mf][nf] = mfma16(afr[mf], bfr[nf], acc[mf][nf]); \
  } while (0)

#define STAGE32(B, K0) do { \
    gload16(ga1 + (K0), &la[(B)*4096 + wid*512]); \
    gload16(ga2 + (K0), &la[(B)*4096 + (wid+4)*512]); \
    gload16(gb1 + (K0), &lb[(B)*4096 + wid*512]); \
    gload16(gb2 + (K0), &lb[(B)*4096 + (wid+4)*512]); \
  } while (0)

// 2-deep counted-vmcnt pipeline (r15 redo with fences):
//  - entered ONLY with vmcnt==0 (preceding __syncthreads drains) so the
//    counted waits see exactly the staging loads (no epilogue pollution);
//  - sched_barrier(0) after every raw s_barrier pins ds_reads / next-stage
//    global_load_lds on the correct side (raw s_barrier is not a fence);
//  - vmcnt(4) leaves next tile's 4 loads in flight across the barrier;
//    in-order retirement guarantees current tile resident. Last step drains.
#define PIPE_LOOP(KDIM) do { \
    int b = 0; \
    STAGE32(0, 0); \
    _Pragma("unroll 1") \
    for (int k0 = 0; k0 < (KDIM); k0 += 32) { \
      if (k0 + 32 < (KDIM)) { \
        STAGE32(b ^ 1, k0 + 32); \
        asm volatile("s_waitcnt vmcnt(4)" ::: "memory"); \
      } else { \
        asm volatile("s_waitcnt vmcnt(0)" ::: "memory"); \
      } \
      __builtin_amdgcn_s_barrier(); \
      __builtin_amdgcn_sched_barrier(0); \
      FRAG_COMPUTE((la + b*4096), (lb + b*4096)); \
      __builtin_amdgcn_s_barrier(); \
      __builtin_amdgcn_sched_barrier(0); \
      b ^= 1; \
    } \
  } while (0)

// ---------------- K4a: grouped GATE GEMM -> G (bf16) into inter --------------
__launch_bounds__(256, 4)
__global__ void k_gate(const u16* __restrict__ xh, const u16* __restrict__ wT,
                       const int* __restrict__ counts, const int* __restrict__ offsets,
                       const int* __restrict__ rows, u16* __restrict__ gout) {
  int wgid = blockIdx.x;
  int xcd = wgid & 7, slot = wgid >> 3;
  int m = slot & 7, q = slot >> 3;
  int g = xcd * 64 + q;
  int e = g >> 3, nb = g & 7;
  int cnt = counts[e];
  if (cnt == 0) return;
  int off = offsets[e];
  int n0 = nb * 128;
  int tid = threadIdx.x, lane = tid & 63, wid = tid >> 6;
  int wm = (wid >> 1) * 64, wn = (wid & 1) * 64;
  __shared__ __align__(16) char smem[32768];
  u16* la = (u16*)smem;                  // [2][128*32] 16 KB (pipeline dbuf)
  u16* lb = (u16*)(smem + 16384);        // [2][128*32] 16 KB (pipeline dbuf)
  u16* lout = (u16*)smem;                // epilogue overlay [64][128] 16 KB
  int rsub = lane >> 2, csub = lane & 3;
  int swzc = csub ^ ((rsub >> 1) & 3);
  int nr1 = wid*16 + rsub, nr2 = nr1 + 64;
  const u16* gb1 = wT + ((size_t)e*FFN + n0 + nr1)*HID + swzc*8;
  const u16* gb2 = wT + ((size_t)e*FFN + n0 + nr2)*HID + swzc*8;

  for (int m0 = m * 128; m0 < cnt; m0 += 1024) {
    int tok1 = (m0 + nr1 < cnt) ? rows[off + m0 + nr1] : 0;
    int tok2 = (m0 + nr2 < cnt) ? rows[off + m0 + nr2] : 0;
    const u16* ga1 = xh + (size_t)tok1*HID + swzc*8;
    const u16* ga2 = xh + (size_t)tok2*HID + swzc*8;
    f32x4 acc[4][4] = {};
    PIPE_LOOP(HID);
    __syncthreads();   // join + drain before lout overlays la
    // epilogue: write G bf16, two 64-row passes through lout overlay
#pragma unroll
    for (int pass = 0; pass < 2; pass++) {
      if ((wid >> 1) == pass) {
#pragma unroll
        for (int mf = 0; mf < 4; mf++)
#pragma unroll
          for (int nf = 0; nf < 4; nf++)
#pragma unroll
            for (int r = 0; r < 4; r++) {
              int row = mf*16 + (lane >> 4)*4 + r;
              int col = wn + nf*16 + (lane & 15);
              U2 t; t.h[0] = (bf16)acc[mf][nf][r]; t.h[1] = (bf16)0.f;
              lout[row*128 + col] = (u16)(t.u & 0xffffu);
            }
      }
      __syncthreads();
      for (int idx = tid; idx < 1024; idx += 256) {
        int row = idx >> 4, c16 = idx & 15;
        int grow = m0 + pass*64 + row;
        if (grow < cnt) {
          uint4 v = *(const uint4*)&lout[row*128 + c16*8];
          *(uint4*)&gout[(size_t)(off + grow)*FFN + n0 + c16*8] = v;
        }
      }
      __syncthreads();   // drains epilogue stores: pipeline entry sees vmcnt==0
    }
  }
}

// ---------------- K4b: grouped UP GEMM; silu fused into the store loop --------
__launch_bounds__(256, 4)
__global__ void k_up(const u16* __restrict__ xh, const u16* __restrict__ wT,
                     const int* __restrict__ counts, const int* __restrict__ offsets,
                     const int* __restrict__ rows, u16* __restrict__ inter) {
  int wgid = blockIdx.x;
  int xcd = wgid & 7, slot = wgid >> 3;
  int m = slot & 7, q = slot >> 3;
  int g = xcd * 64 + q;
  int e = g >> 3, nb = g & 7;
  int cnt = counts[e];
  if (cnt == 0) return;
  int off = offsets[e];
  int n0 = nb * 128;
  int tid = threadIdx.x, lane = tid & 63, wid = tid >> 6;
  int wm = (wid >> 1) * 64, wn = (wid & 1) * 64;
  __shared__ __align__(16) char smem[32768];
  u16* la = (u16*)smem;                  // [2][128*32] 16 KB (pipeline dbuf)
  u16* lb = (u16*)(smem + 16384);        // [2][128*32] 16 KB (pipeline dbuf)
  u16* lout = (u16*)smem;                // epilogue overlay [64][128] 16 KB
  int rsub = lane >> 2, csub = lane & 3;
  int swzc = csub ^ ((rsub >> 1) & 3);
  int nr1 = wid*16 + rsub, nr2 = nr1 + 64;
  const u16* gb1 = wT + ((size_t)e*FFN + n0 + nr1)*HID + swzc*8;
  const u16* gb2 = wT + ((size_t)e*FFN + n0 + nr2)*HID + swzc*8;

  for (int m0 = m * 128; m0 < cnt; m0 += 1024) {
    int tok1 = (m0 + nr1 < cnt) ? rows[off + m0 + nr1] : 0;
    int tok2 = (m0 + nr2 < cnt) ? rows[off + m0 + nr2] : 0;
    const u16* ga1 = xh + (size_t)tok1*HID + swzc*8;
    const u16* ga2 = xh + (size_t)tok2*HID + swzc*8;
    f32x4 acc[4][4] = {};
    PIPE_LOOP(HID);
    __syncthreads();
    // epilogue: U -> lout; fused silu(G)*U in the coalesced store loop
#pragma unroll
    for (int pass = 0; pass < 2; pass++) {
      if ((wid >> 1) == pass) {
#pragma unroll
        for (int mf = 0; mf < 4; mf++)
#pragma unroll
          for (int nf = 0; nf < 4; nf++)
#pragma unroll
            for (int r = 0; r < 4; r++) {
              int row = mf*16 + (lane >> 4)*4 + r;
              int col = wn + nf*16 + (lane & 15);
              U2 t; t.h[0] = (bf16)acc[mf][nf][r]; t.h[1] = (bf16)0.f;
              lout[row*128 + col] = (u16)(t.u & 0xffffu);
            }
      }
      __syncthreads();
      for (int idx = tid; idx < 1024; idx += 256) {
        int row = idx >> 4, c16 = idx & 15;
        int grow = m0 + pass*64 + row;
        if (grow < cnt) {
          size_t base = (size_t)(off + grow)*FFN + n0 + c16*8;
          U8 gv, uv, ov;
          gv.u = *(const uint4*)&inter[base];        // coalesced G read
          uv.u = *(const uint4*)&lout[row*128 + c16*8];
#pragma unroll
          for (int i = 0; i < 8; i++) {
            float gg = (float)gv.h[i];
            float uu = (float)uv.h[i];
            ov.h[i] = (bf16)(gg / (1.f + __expf(-gg)) * uu);
          }
          *(uint4*)&inter[base] = ov.u;              // in-place overwrite
        }
      }
      __syncthreads();
    }
  }
}

// ---------------- K5: grouped down GEMM -> weighted bf16 rows (NO atomics) ----
__launch_bounds__(256, 4)
__global__ void k_expert_down(const u16* __restrict__ inter, const u16* __restrict__ wdT,
                              const int* __restrict__ counts, const int* __restrict__ offsets,
                              const float* __restrict__ rwgt, u16* __restrict__ dscratch) {
  int wgid = blockIdx.x;
  int xcd = wgid & 7, slot = wgid >> 3;
  int m = slot & 3, q = slot >> 2;
  int g = xcd * 128 + q;
  int e = g >> 4, nb = g & 15;
  int cnt = counts[e];
  if (cnt == 0) return;
  int off = offsets[e];
  int n0 = nb * 128;
  int tid = threadIdx.x, lane = tid & 63, wid = tid >> 6;
  int wm = (wid >> 1) * 64, wn = (wid & 1) * 64;
  __shared__ __align__(16) char smem[32768];
  u16* la = (u16*)smem;                  // [2][128*32] 16 KB (pipeline dbuf)
  u16* lb = (u16*)(smem + 16384);        // [2][128*32] 16 KB (pipeline dbuf)
  u16* lout = (u16*)smem;                // epilogue overlay [64][128] 16 KB
  __shared__ float rw_l[128];
  int rsub = lane >> 2, csub = lane & 3;
  int swzc = csub ^ ((rsub >> 1) & 3);
  int nr1 = wid*16 + rsub, nr2 = nr1 + 64;
  const u16* gb1 = wdT + ((size_t)e*HID + n0 + nr1)*FFN + swzc*8;
  const u16* gb2 = wdT + ((size_t)e*HID + n0 + nr2)*FFN + swzc*8;

  for (int m0 = m * 128; m0 < cnt; m0 += 512) {
    __syncthreads();
    if (tid < 128) {
      int r = m0 + tid;
      rw_l[tid] = (r < cnt) ? rwgt[off + r] : 0.f;
    }
    const u16* ga1 = inter + (size_t)(off + m0 + nr1)*FFN + swzc*8;
    const u16* ga2 = inter + (size_t)(off + m0 + nr2)*FFN + swzc*8;
    f32x4 acc[4][4] = {};
    PIPE_LOOP(FFN);
    __syncthreads();
    // epilogue: weighted bf16 store, two 64-row passes through lout overlay
#pragma unroll
    for (int pass = 0; pass < 2; pass++) {
      if ((wid >> 1) == pass) {
#pragma unroll
        for (int mf = 0; mf < 4; mf++)
#pragma unroll
          for (int nf = 0; nf < 4; nf++)
#pragma unroll
            for (int r = 0; r < 4; r++) {
              int row = mf*16 + (lane >> 4)*4 + r;
              int col = wn + nf*16 + (lane & 15);
              float w = rw_l[pass*64 + row];
              U2 t; t.h[0] = (bf16)(w * acc[mf][nf][r]); t.h[1] = (bf16)0.f;
              lout[row*128 + col] = (u16)(t.u & 0xffffu);
            }
      }
      __syncthreads();
      for (int idx = tid; idx < 1024; idx += 256) {
        int row = idx >> 4, c16 = idx & 15;
        int grow = m0 + pass*64 + row;
        if (grow < cnt) {
          uint4 v = *(const uint4*)&lout[row*128 + c16*8];
          *(uint4*)&dscratch[(size_t)(off + grow)*HID + n0 + c16*8] = v;
        }
      }
      __syncthreads();
    }
  }
}

// ---------------- K6: per-token gather-combine ----------------
__global__ void k_combine(const u16* __restrict__ dscratch, const int* __restrict__ slots,
                          float* __restrict__ out) {
  int t = blockIdx.x;
  int tid = threadIdx.x;
  __shared__ int sl[TOPK];
  if (tid < TOPK) sl[tid] = slots[t*TOPK + tid];
  __syncthreads();
  int c = tid * 8;
  float acc[8] = {0.f,0.f,0.f,0.f,0.f,0.f,0.f,0.f};
#pragma unroll
  for (int k = 0; k < TOPK; k++) {
    int p = sl[k];
    if (p >= 0) {
      bf16x8 v = *(const bf16x8*)&dscratch[(size_t)p*HID + c];
#pragma unroll
      for (int i = 0; i < 8; i++) acc[i] += (float)v[i];
    }
  }
  float4 o0 = make_float4(acc[0], acc[1], acc[2], acc[3]);
  float4 o1 = make_float4(acc[4], acc[5], acc[6], acc[7]);
  *(float4*)&out[(size_t)t*HID + c]     = o0;
  *(float4*)&out[(size_t)t*HID + c + 4] = o1;
}

// ---------------- launch ----------------
extern "C" void kernel_launch(void* const* d_in, const int* in_sizes, int n_in,
                              void* d_out, int out_size, void* d_ws, size_t ws_size,
                              hipStream_t stream) {
  const float* x      = (const float*)d_in[0];
  const float* gate_w = (const float*)d_in[1];
  const float* wg     = (const float*)d_in[2];
  const float* wu     = (const float*)d_in[3];
  const float* wd     = (const float*)d_in[4];
  float* out = (float*)d_out;
  float* logits_out = out + (size_t)T_TOK * HID;

  char* w = (char*)d_ws;
  u16* xh = (u16*)w;            w += (size_t)T_TOK*HID*2;
  u16* xl = (u16*)w;            w += (size_t)T_TOK*HID*2;
  u16* gh = (u16*)w;            w += (size_t)NPAD*HID*2;
  u16* gl = (u16*)w;            w += (size_t)NPAD*HID*2;
  int* tk_idx = (int*)w;        w += (size_t)T_TOK*TOPK*4;
  float* tk_w = (float*)w;      w += (size_t)T_TOK*TOPK*4;
  int* counts = (int*)w;        w += 256;
  int* offsets = (int*)w;       w += 256;
  int* cursors = (int*)w;       w += 256;
  int* rows = (int*)w;          w += (size_t)NASSIGN*4;
  float* rwgt = (float*)w;      w += (size_t)NASSIGN*4;
  int* slots = (int*)w;         w += (size_t)NASSIGN*4;
  u16* inter = (u16*)w;         w += ((size_t)NASSIGN + 256)*FFN*2;
  u16* dscratch = (u16*)w;      w += (size_t)NASSIGN*HID*2;
  u16* wgT = (u16*)w;           w += (size_t)NEXP*FFN*HID*2;
  u16* wuT = (u16*)w;           w += (size_t)NEXP*FFN*HID*2;
  u16* wdT = (u16*)w;           // NEXP*HID*FFN*2

  hipMemsetAsync(counts, 0, 256, stream);

  k_prep_x<<<2048, 256, 0, stream>>>(x, xh, xl, T_TOK*HID/8);
  k_prep_gate<<<NPAD, 256, 0, stream>>>(gate_w, gh, gl);
  k_router<<<T_TOK/64, 256, 0, stream>>>(xh, xl, gh, gl, logits_out, tk_idx, tk_w, counts);
  k_scan<<<1, 64, 0, stream>>>(counts, offsets, cursors);
  k_build<<<T_TOK/256, 256, 0, stream>>>(tk_idx, tk_w, cursors, rows, rwgt, slots);

  // one-shot full weight conversion to bf16 [n][k]
  k_convT<<<dim3(FFN/64, HID/128, NEXP), 256, 0, stream>>>(wg, wgT, HID, FFN);
  k_convT<<<dim3(FFN/64, HID/128, NEXP), 256, 0, stream>>>(wu, wuT, HID, FFN);
  k_convT<<<dim3(HID/64, FFN/128, NEXP), 256, 0, stream>>>(wd, wdT, FFN, HID);

  // gate writes G into inter; up computes U and fuses silu(G)*U in its store
  // loop (in-place); down writes weighted bf16 rows; combine gathers per token.
  k_gate<<<4096, 256, 0, stream>>>(xh, wgT, counts, offsets, rows, inter);
  k_up<<<4096, 256, 0, stream>>>(xh, wuT, counts, offsets, rows, inter);
  k_expert_down<<<4096, 256, 0, stream>>>(inter, wdT, counts, offsets, rwgt, dscratch);
  k_combine<<<T_TOK, 256, 0, stream>>>(dscratch, slots, out);
}

// Round 19
// 1761.161 us; speedup vs baseline: 1.0472x; 1.0472x over previous
//
#include <hip/hip_runtime.h>
#include <hip/hip_bf16.h>
#include <stdint.h>

#define T_TOK 8192
#define HID   2048
#define FFN   1024
#define NEXP  64
#define ETOT  72
#define NPAD  80
#define TOPK  8
#define NASSIGN (T_TOK*TOPK)

typedef unsigned short u16;
typedef __bf16 bf16;
typedef bf16 bf16x8 __attribute__((ext_vector_type(8)));
typedef float f32x4 __attribute__((ext_vector_type(4)));

typedef const __attribute__((address_space(1))) void* gp_t;
typedef __attribute__((address_space(3))) void* lp_t;

__device__ __forceinline__ void gload16(const void* g, void* lds) {
  __builtin_amdgcn_global_load_lds((gp_t)g, (lp_t)lds, 16, 0, 0);
}
__device__ __forceinline__ f32x4 mfma16(bf16x8 a, bf16x8 b, f32x4 c) {
  return __builtin_amdgcn_mfma_f32_16x16x32_bf16(a, b, c, 0, 0, 0);
}

union U8 { bf16 h[8]; uint4 u; };
union U2 { bf16 h[2]; unsigned int u; };

// ---------------- K0: fp32 -> bf16 hi/lo split of x ----------------
__global__ void k_prep_x(const float* __restrict__ x, u16* __restrict__ xh,
                         u16* __restrict__ xl, int n8) {
  int i = blockIdx.x * blockDim.x + threadIdx.x;
  int stride = gridDim.x * blockDim.x;
  for (; i < n8; i += stride) {
    const float4* p = (const float4*)(x + (size_t)i * 8);
    float4 a = p[0], b = p[1];
    float f[8] = {a.x,a.y,a.z,a.w,b.x,b.y,b.z,b.w};
    U8 hh, ll;
#pragma unroll
    for (int j = 0; j < 8; j++) {
      bf16 h = (bf16)f[j];
      hh.h[j] = h;
      ll.h[j] = (bf16)(f[j] - (float)h);
    }
    ((uint4*)xh)[i] = hh.u;
    ((uint4*)xl)[i] = ll.u;
  }
}

// ---------------- K0b: gate_w -> bf16 hi/lo, padded to 80 rows ----------------
__global__ void k_prep_gate(const float* __restrict__ gw, u16* __restrict__ gh,
                            u16* __restrict__ gl) {
  int e = blockIdx.x;
  for (int k8 = threadIdx.x; k8 < HID/8; k8 += blockDim.x) {
    U8 hh, ll;
    if (e < ETOT) {
      const float4* p = (const float4*)(gw + (size_t)e*HID + k8*8);
      float4 a = p[0], b = p[1];
      float f[8] = {a.x,a.y,a.z,a.w,b.x,b.y,b.z,b.w};
#pragma unroll
      for (int j = 0; j < 8; j++) {
        bf16 h = (bf16)f[j]; hh.h[j] = h; ll.h[j] = (bf16)(f[j]-(float)h);
      }
    } else {
      hh.u = make_uint4(0,0,0,0); ll.u = make_uint4(0,0,0,0);
    }
    ((uint4*)gh)[(size_t)e*(HID/8) + k8] = hh.u;
    ((uint4*)gl)[(size_t)e*(HID/8) + k8] = ll.u;
  }
}

// ---------------- K0c: fp32 [R][C] -> bf16 [C][R] transpose-convert ----------
// pad 134: LDS write bank conflicts 4-way -> 2-way (2-way is free).
__global__ void k_convT(const float* __restrict__ src, u16* __restrict__ dst,
                        int R, int C) {
  int e = blockIdx.z;
  src += (size_t)e * R * C;
  dst += (size_t)e * R * C;
  int c0 = blockIdx.x * 64, r0 = blockIdx.y * 128;
  __shared__ u16 t[64 * 134];
  int tid = threadIdx.x;
  int rr = tid >> 4, cc = (tid & 15) * 4;
#pragma unroll
  for (int it = 0; it < 8; it++) {
    int r = it * 16 + rr;
    float4 v = *(const float4*)(src + (size_t)(r0 + r) * C + c0 + cc);
    const float* f = &v.x;
#pragma unroll
    for (int i = 0; i < 4; i++) {
      U2 u; u.h[0] = (bf16)f[i]; u.h[1] = (bf16)0.f;
      t[(cc + i) * 134 + r] = (u16)(u.u & 0xffffu);
    }
  }
  __syncthreads();
  int n = tid >> 2, kb = (tid & 3) * 32;
  u16* drow = dst + (size_t)(c0 + n) * R + r0 + kb;
  const u16* srow = &t[n * 134 + kb];
#pragma unroll
  for (int j = 0; j < 2; j++) {
    uint2 a = *(const uint2*)&srow[j*16 + 0];
    uint2 b = *(const uint2*)&srow[j*16 + 4];
    uint2 c = *(const uint2*)&srow[j*16 + 8];
    uint2 d = *(const uint2*)&srow[j*16 + 12];
    *(uint4*)&drow[j*16]     = make_uint4(a.x, a.y, b.x, b.y);
    *(uint4*)&drow[j*16 + 8] = make_uint4(c.x, c.y, d.x, d.y);
  }
}

// ---------------- K1: router ----------------
__global__ void k_router(const u16* __restrict__ xh, const u16* __restrict__ xl,
                         const u16* __restrict__ gh, const u16* __restrict__ gl,
                         float* __restrict__ logits_out, int* __restrict__ tk_idx,
                         float* __restrict__ tk_w, int* __restrict__ counts) {
  __shared__ u16 la_h[64*32], la_l[64*32], lb_h[NPAD*32], lb_l[NPAD*32];
  __shared__ float llog[64*NPAD];
  int tid = threadIdx.x, lane = tid & 63, wid = tid >> 6;
  int t0 = blockIdx.x * 64;
  int rsub = lane >> 2, csub = lane & 3;
  f32x4 acc[5] = {};
#pragma unroll 1
  for (int k0 = 0; k0 < HID; k0 += 32) {
    int arow = wid*16 + rsub;
    gload16(xh + (size_t)(t0+arow)*HID + k0 + csub*8, &la_h[wid*512]);
    gload16(xl + (size_t)(t0+arow)*HID + k0 + csub*8, &la_l[wid*512]);
    int brow = wid*16 + rsub;
    gload16(gh + (size_t)brow*HID + k0 + csub*8, &lb_h[wid*512]);
    gload16(gl + (size_t)brow*HID + k0 + csub*8, &lb_l[wid*512]);
    if (wid == 0) gload16(gh + (size_t)(64+rsub)*HID + k0 + csub*8, &lb_h[4*512]);
    if (wid == 1) gload16(gl + (size_t)(64+rsub)*HID + k0 + csub*8, &lb_l[4*512]);
    __syncthreads();
    int ar = wid*16 + (lane & 15);
    int ks = lane >> 4;
    bf16x8 ah = *(const bf16x8*)&la_h[ar*32 + ks*8];
    bf16x8 al = *(const bf16x8*)&la_l[ar*32 + ks*8];
#pragma unroll
    for (int nf = 0; nf < 5; nf++) {
      int br = nf*16 + (lane & 15);
      bf16x8 bh = *(const bf16x8*)&lb_h[br*32 + ks*8];
      bf16x8 bl = *(const bf16x8*)&lb_l[br*32 + ks*8];
      acc[nf] = mfma16(ah, bh, acc[nf]);
      acc[nf] = mfma16(ah, bl, acc[nf]);
      acc[nf] = mfma16(al, bh, acc[nf]);
    }
    __syncthreads();
  }
  {
    int q = lane >> 4, c = lane & 15;
#pragma unroll
    for (int nf = 0; nf < 5; nf++)
#pragma unroll
      for (int r = 0; r < 4; r++)
        llog[(wid*16 + q*4 + r)*NPAD + nf*16 + c] = acc[nf][r];
  }
  __syncthreads();
  if (tid < 64) {
    int t = t0 + tid;
    float* lg = &llog[tid*NPAD];
    float m = -1e30f;
    for (int e = 0; e < ETOT; e++) {
      float v = lg[e];
      logits_out[(size_t)t*ETOT + e] = v;
      m = fmaxf(m, v);
    }
    float s = 0.f;
    for (int e = 0; e < ETOT; e++) s += __expf(lg[e] - m);
    uint64_t m0 = 0; unsigned int m1 = 0;
    for (int k = 0; k < TOPK; k++) {
      float best = -1e30f; int bi = 0;
      for (int e = 0; e < ETOT; e++) {
        bool used = (e < 64) ? ((m0 >> e) & 1) : ((m1 >> (e-64)) & 1);
        float v = lg[e];
        if (!used && v > best) { best = v; bi = e; }
      }
      if (bi < 64) m0 |= (1ull << bi); else m1 |= (1u << (bi-64));
      tk_idx[t*TOPK + k] = bi;
      tk_w[t*TOPK + k] = __expf(best - m) / s;
      if (bi < NEXP) atomicAdd(&counts[bi], 1);
    }
  }
}

// ---------------- K2: scan ----------------
__global__ void k_scan(const int* __restrict__ counts, int* __restrict__ offsets,
                       int* __restrict__ cursors) {
  if (threadIdx.x == 0) {
    int s = 0;
    for (int e = 0; e < NEXP; e++) { offsets[e] = s; cursors[e] = s; s += counts[e]; }
  }
}

// ---------------- K3: build grouped lists (+ per-token slot map) ----------------
__global__ void k_build(const int* __restrict__ tk_idx, const float* __restrict__ tk_w,
                        int* __restrict__ cursors, int* __restrict__ rows,
                        float* __restrict__ rwgt, int* __restrict__ slots) {
  int t = blockIdx.x * blockDim.x + threadIdx.x;
  if (t >= T_TOK) return;
#pragma unroll
  for (int k = 0; k < TOPK; k++) {
    int e = tk_idx[t*TOPK + k];
    if (e < NEXP) {
      int p = atomicAdd(&cursors[e], 1);
      rows[p] = t;
      rwgt[p] = tk_w[t*TOPK + k];
      slots[t*TOPK + k] = p;
    } else {
      slots[t*TOPK + k] = -1;
    }
  }
}

// Shared fragment-compute body (r10/r12-verified math).
#define FRAG_COMPUTE(LAP, LBP) do { \
    bf16x8 afr[4], bfr[4]; \
    _Pragma("unroll") \
    for (int i = 0; i < 4; i++) { \
      int row = wm + i*16 + (lane & 15); \
      int ch = (lane >> 4) ^ ((row >> 1) & 3); \
      afr[i] = *(const bf16x8*)&(LAP)[row*32 + ch*8]; \
      int n = wn + i*16 + (lane & 15); \
      int chb = (lane >> 4) ^ ((n >> 1) & 3); \
      bfr[i] = *(const bf16x8*)&(LBP)[n*32 + chb*8]; \
    } \
    _Pragma("unroll") \
    for (int nf = 0; nf < 4; nf++) \
      _Pragma("unroll") \
      for (int mf = 0; mf < 4; mf++) \
        acc[mf][nf] = mfma16(afr[mf], bfr[nf], acc[mf][nf]); \
  } while (0)

// BK=64 lockstep step (r13-verified): stage two 32-wide K-slices, ONE barrier,
// compute both sub-tiles, ONE barrier.
#define BK64_LOOP(KDIM) \
    _Pragma("unroll 1") \
    for (int k0 = 0; k0 < (KDIM); k0 += 64) { \
      gload16(ga1 + k0, &la[wid*512]); \
      gload16(ga2 + k0, &la[(wid+4)*512]); \
      gload16(gb1 + k0, &lb[wid*512]); \
      gload16(gb2 + k0, &lb[(wid+4)*512]); \
      gload16(ga1 + k0 + 32, &la[4096 + wid*512]); \
      gload16(ga2 + k0 + 32, &la[4096 + (wid+4)*512]); \
      gload16(gb1 + k0 + 32, &lb[4096 + wid*512]); \
      gload16(gb2 + k0 + 32, &lb[4096 + (wid+4)*512]); \
      __syncthreads(); \
      FRAG_COMPUTE(la, lb); \
      FRAG_COMPUTE((la + 4096), (lb + 4096)); \
      __syncthreads(); \
    }

// ---------------- K4a: grouped GATE GEMM -> G (bf16) into inter --------------
__launch_bounds__(256, 4)
__global__ void k_gate(const u16* __restrict__ xh, const u16* __restrict__ wT,
                       const int* __restrict__ counts, const int* __restrict__ offsets,
                       const int* __restrict__ rows, u16* __restrict__ gout) {
  int wgid = blockIdx.x;
  int xcd = wgid & 7, slot = wgid >> 3;
  int m = slot & 7, q = slot >> 3;
  int g = xcd * 64 + q;
  int e = g >> 3, nb = g & 7;
  int cnt = counts[e];
  if (cnt == 0) return;
  int off = offsets[e];
  int n0 = nb * 128;
  int tid = threadIdx.x, lane = tid & 63, wid = tid >> 6;
  int wm = (wid >> 1) * 64, wn = (wid & 1) * 64;
  __shared__ __align__(16) char smem[32768];
  u16* la = (u16*)smem;                  // [2][128*32] 16 KB
  u16* lb = (u16*)(smem + 16384);        // [2][128*32] 16 KB
  u16* lout = (u16*)smem;                // epilogue overlay [64][128] 16 KB
  int rsub = lane >> 2, csub = lane & 3;
  int swzc = csub ^ ((rsub >> 1) & 3);
  int nr1 = wid*16 + rsub, nr2 = nr1 + 64;
  const u16* gb1 = wT + ((size_t)e*FFN + n0 + nr1)*HID + swzc*8;
  const u16* gb2 = wT + ((size_t)e*FFN + n0 + nr2)*HID + swzc*8;

  for (int m0 = m * 128; m0 < cnt; m0 += 1024) {
    int tok1 = (m0 + nr1 < cnt) ? rows[off + m0 + nr1] : 0;
    int tok2 = (m0 + nr2 < cnt) ? rows[off + m0 + nr2] : 0;
    const u16* ga1 = xh + (size_t)tok1*HID + swzc*8;
    const u16* ga2 = xh + (size_t)tok2*HID + swzc*8;
    f32x4 acc[4][4] = {};
    BK64_LOOP(HID)
    // epilogue: write G bf16, two 64-row passes through lout overlay
#pragma unroll
    for (int pass = 0; pass < 2; pass++) {
      if ((wid >> 1) == pass) {
#pragma unroll
        for (int mf = 0; mf < 4; mf++)
#pragma unroll
          for (int nf = 0; nf < 4; nf++)
#pragma unroll
            for (int r = 0; r < 4; r++) {
              int row = mf*16 + (lane >> 4)*4 + r;
              int col = wn + nf*16 + (lane & 15);
              U2 t; t.h[0] = (bf16)acc[mf][nf][r]; t.h[1] = (bf16)0.f;
              lout[row*128 + col] = (u16)(t.u & 0xffffu);
            }
      }
      __syncthreads();
      for (int idx = tid; idx < 1024; idx += 256) {
        int row = idx >> 4, c16 = idx & 15;
        int grow = m0 + pass*64 + row;
        if (grow < cnt) {
          uint4 v = *(const uint4*)&lout[row*128 + c16*8];
          *(uint4*)&gout[(size_t)(off + grow)*FFN + n0 + c16*8] = v;
        }
      }
      __syncthreads();
    }
  }
}

// ---------------- K4b: grouped UP GEMM; silu fused into the store loop --------
// Epilogue: write U (bf16) to lout; store loop reads G from inter with the SAME
// coalesced pattern as the store, applies silu(G)*U elementwise, writes back in
// place. No LDS G-staging pass, one fewer barrier per pass.
__launch_bounds__(256, 4)
__global__ void k_up(const u16* __restrict__ xh, const u16* __restrict__ wT,
                     const int* __restrict__ counts, const int* __restrict__ offsets,
                     const int* __restrict__ rows, u16* __restrict__ inter) {
  int wgid = blockIdx.x;
  int xcd = wgid & 7, slot = wgid >> 3;
  int m = slot & 7, q = slot >> 3;
  int g = xcd * 64 + q;
  int e = g >> 3, nb = g & 7;
  int cnt = counts[e];
  if (cnt == 0) return;
  int off = offsets[e];
  int n0 = nb * 128;
  int tid = threadIdx.x, lane = tid & 63, wid = tid >> 6;
  int wm = (wid >> 1) * 64, wn = (wid & 1) * 64;
  __shared__ __align__(16) char smem[32768];
  u16* la = (u16*)smem;                  // [2][128*32] 16 KB
  u16* lb = (u16*)(smem + 16384);        // [2][128*32] 16 KB
  u16* lout = (u16*)smem;                // epilogue overlay [64][128] 16 KB
  int rsub = lane >> 2, csub = lane & 3;
  int swzc = csub ^ ((rsub >> 1) & 3);
  int nr1 = wid*16 + rsub, nr2 = nr1 + 64;
  const u16* gb1 = wT + ((size_t)e*FFN + n0 + nr1)*HID + swzc*8;
  const u16* gb2 = wT + ((size_t)e*FFN + n0 + nr2)*HID + swzc*8;

  for (int m0 = m * 128; m0 < cnt; m0 += 1024) {
    int tok1 = (m0 + nr1 < cnt) ? rows[off + m0 + nr1] : 0;
    int tok2 = (m0 + nr2 < cnt) ? rows[off + m0 + nr2] : 0;
    const u16* ga1 = xh + (size_t)tok1*HID + swzc*8;
    const u16* ga2 = xh + (size_t)tok2*HID + swzc*8;
    f32x4 acc[4][4] = {};
    BK64_LOOP(HID)
    // epilogue: U -> lout; fused silu(G)*U in the coalesced store loop
#pragma unroll
    for (int pass = 0; pass < 2; pass++) {
      if ((wid >> 1) == pass) {
#pragma unroll
        for (int mf = 0; mf < 4; mf++)
#pragma unroll
          for (int nf = 0; nf < 4; nf++)
#pragma unroll
            for (int r = 0; r < 4; r++) {
              int row = mf*16 + (lane >> 4)*4 + r;
              int col = wn + nf*16 + (lane & 15);
              U2 t; t.h[0] = (bf16)acc[mf][nf][r]; t.h[1] = (bf16)0.f;
              lout[row*128 + col] = (u16)(t.u & 0xffffu);
            }
      }
      __syncthreads();
      for (int idx = tid; idx < 1024; idx += 256) {
        int row = idx >> 4, c16 = idx & 15;
        int grow = m0 + pass*64 + row;
        if (grow < cnt) {
          size_t base = (size_t)(off + grow)*FFN + n0 + c16*8;
          U8 gv, uv, ov;
          gv.u = *(const uint4*)&inter[base];        // coalesced G read
          uv.u = *(const uint4*)&lout[row*128 + c16*8];
#pragma unroll
          for (int i = 0; i < 8; i++) {
            float gg = (float)gv.h[i];
            float uu = (float)uv.h[i];
            ov.h[i] = (bf16)(gg / (1.f + __expf(-gg)) * uu);
          }
          *(uint4*)&inter[base] = ov.u;              // in-place overwrite
        }
      }
      __syncthreads();
    }
  }
}

// ---------------- K5: grouped down GEMM -> weighted bf16 rows (NO atomics) ----
__launch_bounds__(256, 4)
__global__ void k_expert_down(const u16* __restrict__ inter, const u16* __restrict__ wdT,
                              const int* __restrict__ counts, const int* __restrict__ offsets,
                              const float* __restrict__ rwgt, u16* __restrict__ dscratch) {
  int wgid = blockIdx.x;
  int xcd = wgid & 7, slot = wgid >> 3;
  int m = slot & 3, q = slot >> 2;
  int g = xcd * 128 + q;
  int e = g >> 4, nb = g & 15;
  int cnt = counts[e];
  if (cnt == 0) return;
  int off = offsets[e];
  int n0 = nb * 128;
  int tid = threadIdx.x, lane = tid & 63, wid = tid >> 6;
  int wm = (wid >> 1) * 64, wn = (wid & 1) * 64;
  __shared__ __align__(16) char smem[32768];
  u16* la = (u16*)smem;                  // [2][128*32] 16 KB
  u16* lb = (u16*)(smem + 16384);        // [2][128*32] 16 KB
  u16* lout = (u16*)smem;                // epilogue overlay [64][128] 16 KB
  __shared__ float rw_l[128];
  int rsub = lane >> 2, csub = lane & 3;
  int swzc = csub ^ ((rsub >> 1) & 3);
  int nr1 = wid*16 + rsub, nr2 = nr1 + 64;
  const u16* gb1 = wdT + ((size_t)e*HID + n0 + nr1)*FFN + swzc*8;
  const u16* gb2 = wdT + ((size_t)e*HID + n0 + nr2)*FFN + swzc*8;

  for (int m0 = m * 128; m0 < cnt; m0 += 512) {
    __syncthreads();
    if (tid < 128) {
      int r = m0 + tid;
      rw_l[tid] = (r < cnt) ? rwgt[off + r] : 0.f;
    }
    const u16* ga1 = inter + (size_t)(off + m0 + nr1)*FFN + swzc*8;
    const u16* ga2 = inter + (size_t)(off + m0 + nr2)*FFN + swzc*8;
    f32x4 acc[4][4] = {};
    BK64_LOOP(FFN)
    // epilogue: weighted bf16 store, two 64-row passes through lout overlay
#pragma unroll
    for (int pass = 0; pass < 2; pass++) {
      if ((wid >> 1) == pass) {
#pragma unroll
        for (int mf = 0; mf < 4; mf++)
#pragma unroll
          for (int nf = 0; nf < 4; nf++)
#pragma unroll
            for (int r = 0; r < 4; r++) {
              int row = mf*16 + (lane >> 4)*4 + r;
              int col = wn + nf*16 + (lane & 15);
              float w = rw_l[pass*64 + row];
              U2 t; t.h[0] = (bf16)(w * acc[mf][nf][r]); t.h[1] = (bf16)0.f;
              lout[row*128 + col] = (u16)(t.u & 0xffffu);
            }
      }
      __syncthreads();
      for (int idx = tid; idx < 1024; idx += 256) {
        int row = idx >> 4, c16 = idx & 15;
        int grow = m0 + pass*64 + row;
        if (grow < cnt) {
          uint4 v = *(const uint4*)&lout[row*128 + c16*8];
          *(uint4*)&dscratch[(size_t)(off + grow)*HID + n0 + c16*8] = v;
        }
      }
      __syncthreads();
    }
  }
}

// ---------------- K6: per-token gather-combine ----------------
__global__ void k_combine(const u16* __restrict__ dscratch, const int* __restrict__ slots,
                          float* __restrict__ out) {
  int t = blockIdx.x;
  int tid = threadIdx.x;
  __shared__ int sl[TOPK];
  if (tid < TOPK) sl[tid] = slots[t*TOPK + tid];
  __syncthreads();
  int c = tid * 8;
  float acc[8] = {0.f,0.f,0.f,0.f,0.f,0.f,0.f,0.f};
#pragma unroll
  for (int k = 0; k < TOPK; k++) {
    int p = sl[k];
    if (p >= 0) {
      bf16x8 v = *(const bf16x8*)&dscratch[(size_t)p*HID + c];
#pragma unroll
      for (int i = 0; i < 8; i++) acc[i] += (float)v[i];
    }
  }
  float4 o0 = make_float4(acc[0], acc[1], acc[2], acc[3]);
  float4 o1 = make_float4(acc[4], acc[5], acc[6], acc[7]);
  *(float4*)&out[(size_t)t*HID + c]     = o0;
  *(float4*)&out[(size_t)t*HID + c + 4] = o1;
}

// ---------------- launch ----------------
extern "C" void kernel_launch(void* const* d_in, const int* in_sizes, int n_in,
                              void* d_out, int out_size, void* d_ws, size_t ws_size,
                              hipStream_t stream) {
  const float* x      = (const float*)d_in[0];
  const float* gate_w = (const float*)d_in[1];
  const float* wg     = (const float*)d_in[2];
  const float* wu     = (const float*)d_in[3];
  const float* wd     = (const float*)d_in[4];
  float* out = (float*)d_out;
  float* logits_out = out + (size_t)T_TOK * HID;

  char* w = (char*)d_ws;
  u16* xh = (u16*)w;            w += (size_t)T_TOK*HID*2;
  u16* xl = (u16*)w;            w += (size_t)T_TOK*HID*2;
  u16* gh = (u16*)w;            w += (size_t)NPAD*HID*2;
  u16* gl = (u16*)w;            w += (size_t)NPAD*HID*2;
  int* tk_idx = (int*)w;        w += (size_t)T_TOK*TOPK*4;
  float* tk_w = (float*)w;      w += (size_t)T_TOK*TOPK*4;
  int* counts = (int*)w;        w += 256;
  int* offsets = (int*)w;       w += 256;
  int* cursors = (int*)w;       w += 256;
  int* rows = (int*)w;          w += (size_t)NASSIGN*4;
  float* rwgt = (float*)w;      w += (size_t)NASSIGN*4;
  int* slots = (int*)w;         w += (size_t)NASSIGN*4;
  u16* inter = (u16*)w;         w += ((size_t)NASSIGN + 256)*FFN*2;
  u16* dscratch = (u16*)w;      w += (size_t)NASSIGN*HID*2;
  u16* wgT = (u16*)w;           w += (size_t)NEXP*FFN*HID*2;
  u16* wuT = (u16*)w;           w += (size_t)NEXP*FFN*HID*2;
  u16* wdT = (u16*)w;           // NEXP*HID*FFN*2

  hipMemsetAsync(counts, 0, 256, stream);

  k_prep_x<<<2048, 256, 0, stream>>>(x, xh, xl, T_TOK*HID/8);
  k_prep_gate<<<NPAD, 256, 0, stream>>>(gate_w, gh, gl);
  k_router<<<T_TOK/64, 256, 0, stream>>>(xh, xl, gh, gl, logits_out, tk_idx, tk_w, counts);
  k_scan<<<1, 64, 0, stream>>>(counts, offsets, cursors);
  k_build<<<T_TOK/256, 256, 0, stream>>>(tk_idx, tk_w, cursors, rows, rwgt, slots);

  // one-shot full weight conversion to bf16 [n][k]
  k_convT<<<dim3(FFN/64, HID/128, NEXP), 256, 0, stream>>>(wg, wgT, HID, FFN);
  k_convT<<<dim3(FFN/64, HID/128, NEXP), 256, 0, stream>>>(wu, wuT, HID, FFN);
  k_convT<<<dim3(HID/64, FFN/128, NEXP), 256, 0, stream>>>(wd, wdT, FFN, HID);

  // gate writes G into inter; up computes U and fuses silu(G)*U in its store
  // loop (in-place); down writes weighted bf16 rows; combine gathers per token.
  k_gate<<<4096, 256, 0, stream>>>(xh, wgT, counts, offsets, rows, inter);
  k_up<<<4096, 256, 0, stream>>>(xh, wuT, counts, offsets, rows, inter);
  k_expert_down<<<4096, 256, 0, stream>>>(inter, wdT, counts, offsets, rwgt, dscratch);
  k_combine<<<T_TOK, 256, 0, stream>>>(dscratch, slots, out);
}